// Round 3
// baseline (11863.014 us; speedup 1.0000x reference)
//
#include <hip/hip_runtime.h>
#include <cstdint>

#define DEVI __device__ __forceinline__

typedef unsigned short u16;
typedef __bf16 bf16x8 __attribute__((ext_vector_type(8)));
typedef u16 u16x8 __attribute__((ext_vector_type(8)));
typedef float f32x4 __attribute__((ext_vector_type(4)));

// B=32, T=128 (127 decode steps), V=32000, E=256, U=AU=M=1024, S=128
#define NB 32
#define NT 127
#define NV 32000
#define NE 256
#define NU 1024
#define NBLK 256

DEVI float b2f(u16 h){ union{unsigned u; float f;} v; v.u = ((unsigned)h)<<16; return v.f; }
DEVI u16 f2b(float f){ union{float f; unsigned u;} v; v.f=f; unsigned u=v.u;
                       return (u16)((u + 0x7fffu + ((u>>16)&1u))>>16); }
DEVI float sigm(float x){ return 1.f/(1.f+__expf(-x)); }
DEVI float tanh_(float x){ return 1.f - 2.f/(1.f+__expf(2.f*x)); }
#define MFMA __builtin_amdgcn_mfma_f32_16x16x32_bf16

// ---------------- small conversion kernels ----------------
__global__ void k_conv(const float* __restrict__ s, u16* __restrict__ d, int n){
  for (int i = blockIdx.x*256 + threadIdx.x; i < n; i += gridDim.x*256) d[i] = f2b(s[i]);
}
__global__ void k_split(const float* __restrict__ s, u16* __restrict__ dh, u16* __restrict__ dl, int n){
  for (int i = blockIdx.x*256 + threadIdx.x; i < n; i += gridDim.x*256){
    float v = s[i]; u16 hi = f2b(v); dh[i]=hi; dl[i]=f2b(v-b2f(hi));
  }
}
__global__ void k_gather(const int* __restrict__ toks, const float* __restrict__ emb, u16* __restrict__ x){
  int i = blockIdx.x*256 + threadIdx.x;
  if (i >= NB*NT*NE) return;
  int bt = i>>8, e = i&255;
  int b = bt/NT, t = bt - b*NT;
  int tok = toks[b*128 + t];                 // dec_in = output_batch[:, :-1]
  x[i] = f2b(emb[(size_t)tok*NE + e]);
}
// transpose f32 (R x C, row stride rs) -> bf16 hi/lo (C x dstStride) at dst[c*dstStride+dstOff+r]
__global__ void k_transpose(const float* __restrict__ src, int rs,
                            u16* __restrict__ dh, u16* __restrict__ dl,
                            int dstStride, int dstOff){
  __shared__ float tile[32][33];
  int tc = blockIdx.x*32, tr = blockIdx.y*32;
  int tx = threadIdx.x & 31, ty = threadIdx.x >> 5;
  #pragma unroll
  for (int rr=0; rr<4; ++rr){
    int r = ty + rr*8;
    tile[r][tx] = src[(size_t)(tr+r)*rs + tc + tx];
  }
  __syncthreads();
  #pragma unroll
  for (int rr=0; rr<4; ++rr){
    int cl = ty + rr*8;
    float v = tile[tx][cl];
    u16 hi = f2b(v);
    size_t o = (size_t)(tc+cl)*dstStride + dstOff + tr + tx;
    dh[o] = hi;
    if (dl) dl[o] = f2b(v - b2f(hi));
  }
}
// transpose+add f32 C[1024][4096] (+addS) -> bf16 hi/lo dst[4096][1024]
__global__ void k_fuseT(const float* __restrict__ C, const float* __restrict__ addS,
                        u16* __restrict__ dh, u16* __restrict__ dl){
  __shared__ float tile[32][33];
  int tc = blockIdx.x*32, tr = blockIdx.y*32;
  int tx = threadIdx.x & 31, ty = threadIdx.x >> 5;
  #pragma unroll
  for (int rr=0; rr<4; ++rr){
    int r = ty + rr*8;
    float v = C[(size_t)(tr+r)*4096 + tc + tx];
    if (addS) v += addS[(size_t)(tr+r)*4096 + tc + tx];
    tile[r][tx] = v;
  }
  __syncthreads();
  #pragma unroll
  for (int rr=0; rr<4; ++rr){
    int cl = ty + rr*8;
    float v = tile[tx][cl];
    u16 hi = f2b(v);
    size_t o = (size_t)(tc+cl)*1024 + tr + tx;
    dh[o] = hi; dl[o] = f2b(v - b2f(hi));
  }
}

// ---------------- generic 64x64-tile bf16 MFMA GEMM (single-term) ----------------
template<int OUTF, int BIAS>
__global__ __launch_bounds__(256) void k_gemm64(
    const u16* __restrict__ A, int lda,
    const u16* __restrict__ Bt, int ldb,
    float* __restrict__ Cf, u16* __restrict__ Cb, int ldc,
    const float* __restrict__ bias, int M, int K)
{
  __shared__ __align__(16) u16 As[64][40];
  __shared__ __align__(16) u16 Bs[64][40];
  int n0 = blockIdx.x*64, m0 = blockIdx.y*64;
  int tid = threadIdx.x, lane = tid & 63, w = tid>>6;
  int lr = tid>>2, lk = (tid&3)*8;
  f32x4 acc[4] = {};
  for (int kk=0; kk<K; kk+=32){
    uint4 av = make_uint4(0,0,0,0);
    int row = m0 + lr;
    if (row < M) av = *(const uint4*)(A + (size_t)row*lda + kk + lk);
    *(uint4*)(&As[lr][lk]) = av;
    uint4 bv = *(const uint4*)(Bt + (size_t)(n0+lr)*ldb + kk + lk);
    *(uint4*)(&Bs[lr][lk]) = bv;
    __syncthreads();
    bf16x8 af = *(const bf16x8*)(&As[w*16 + (lane&15)][(lane>>4)*8]);
    #pragma unroll
    for (int ni=0; ni<4; ++ni){
      bf16x8 bfr = *(const bf16x8*)(&Bs[ni*16 + (lane&15)][(lane>>4)*8]);
      acc[ni] = MFMA(af, bfr, acc[ni], 0,0,0);
    }
    __syncthreads();
  }
  #pragma unroll
  for (int ni=0; ni<4; ++ni){
    #pragma unroll
    for (int r=0; r<4; ++r){
      int row = m0 + w*16 + (lane>>4)*4 + r;
      int col = n0 + ni*16 + (lane&15);
      if (row < M){
        float v = acc[ni][r];
        if (BIAS) v += bias[col];
        if (OUTF==0) Cf[(size_t)row*ldc + col] = v;
        else         Cb[(size_t)row*ldc + col] = f2b(v);
      }
    }
  }
}

// ---------------- 3-term split-precision 64x64 GEMM: (Ah+Al) x (Bh+Bl) ----------------
template<int OUTF>
__global__ __launch_bounds__(256) void k_gemm64s(
    const u16* __restrict__ Ah, const u16* __restrict__ Al, int lda,
    const u16* __restrict__ Bh, const u16* __restrict__ Bl, int ldb,
    float* __restrict__ Cf, u16* __restrict__ Cb, int ldc, int M, int K)
{
  __shared__ __align__(16) u16 Ash[64][40], Asl[64][40], Bsh[64][40], Bsl[64][40];
  int n0 = blockIdx.x*64, m0 = blockIdx.y*64;
  int tid = threadIdx.x, lane = tid & 63, w = tid>>6;
  int lr = tid>>2, lk = (tid&3)*8;
  f32x4 acc[4] = {};
  for (int kk=0; kk<K; kk+=32){
    uint4 avh = make_uint4(0,0,0,0), avl = make_uint4(0,0,0,0);
    int row = m0 + lr;
    if (row < M){
      avh = *(const uint4*)(Ah + (size_t)row*lda + kk + lk);
      avl = *(const uint4*)(Al + (size_t)row*lda + kk + lk);
    }
    *(uint4*)(&Ash[lr][lk]) = avh;
    *(uint4*)(&Asl[lr][lk]) = avl;
    *(uint4*)(&Bsh[lr][lk]) = *(const uint4*)(Bh + (size_t)(n0+lr)*ldb + kk + lk);
    *(uint4*)(&Bsl[lr][lk]) = *(const uint4*)(Bl + (size_t)(n0+lr)*ldb + kk + lk);
    __syncthreads();
    bf16x8 afh = *(const bf16x8*)(&Ash[w*16 + (lane&15)][(lane>>4)*8]);
    bf16x8 afl = *(const bf16x8*)(&Asl[w*16 + (lane&15)][(lane>>4)*8]);
    #pragma unroll
    for (int ni=0; ni<4; ++ni){
      bf16x8 bfh = *(const bf16x8*)(&Bsh[ni*16 + (lane&15)][(lane>>4)*8]);
      bf16x8 bfl = *(const bf16x8*)(&Bsl[ni*16 + (lane&15)][(lane>>4)*8]);
      acc[ni] = MFMA(afh, bfl, acc[ni], 0,0,0);
      acc[ni] = MFMA(afl, bfh, acc[ni], 0,0,0);
      acc[ni] = MFMA(afh, bfh, acc[ni], 0,0,0);
    }
    __syncthreads();
  }
  #pragma unroll
  for (int ni=0; ni<4; ++ni){
    #pragma unroll
    for (int r=0; r<4; ++r){
      int row = m0 + w*16 + (lane>>4)*4 + r;
      int col = n0 + ni*16 + (lane&15);
      if (row < M){
        float v = acc[ni][r];
        if (OUTF==0) Cf[(size_t)row*ldc + col] = v;
        else         Cb[(size_t)row*ldc + col] = f2b(v);
      }
    }
  }
}

// ---------------- persistent recurrence kernel ----------------
struct PP {
  const u16 *WzhTH, *WzhTL;   // [4096][1024]
  const u16 *WzcTH, *WzcTL;   // [4096][1024]
  const u16 *Wr0TH, *Wr0TL;   // [4096][1024] (t=0 h-weight = W_r^T)
  const u16 *WqT;             // [1024][1024]
  const u16 *xW;              // rows b*NT+t, 4096 cols (bf16, bias folded)
  const u16 *keys;            // [4096][1024]
  const u16 *aB;              // [4096][1024]
  const float *v_att;         // [1024]
  const u16 *h0H, *h0L;       // [32][1024]
  u16 *hH0,*hL0,*hH1,*hL1;    // ping-pong h
  u16 *ctxH, *ctxL;           // [32][1024] (zero-init)
  float *cbuf;                // [32][1024] (init c_tx)
  float *qf;                  // [32][1024]
  float *scf;                 // [32][128]
  u16 *hcH, *hcL;             // [4096][2048] hist [h | ctx]
  unsigned *bar;
};

DEVI void gbar(unsigned* bar, unsigned& gen){
  gen += 1;
  __syncthreads();
  if (threadIdx.x == 0){
    __hip_atomic_fetch_add(bar, 1u, __ATOMIC_RELEASE, __HIP_MEMORY_SCOPE_AGENT);
    unsigned tgt = gen*(unsigned)NBLK;
    while (__hip_atomic_load(bar, __ATOMIC_RELAXED, __HIP_MEMORY_SCOPE_AGENT) < tgt)
      __builtin_amdgcn_s_sleep(1);
    __builtin_amdgcn_fence(__ATOMIC_ACQUIRE, "agent");
  }
  __syncthreads();
}

__global__ __launch_bounds__(512,1) void k_persist(PP p){
  __shared__ float smem[4096];   // 16 KB: zs[8][32][16] / alig[128]+psum[8][128]
  float (*zs)[32][16] = (float(*)[32][16])smem;
  int tid = threadIdx.x, lane = tid&63, wv = tid>>6, blk = blockIdx.x;
  int l15 = lane&15, ko = (lane>>4)*8;
  unsigned gen = 0;
  const u16 *hpH = p.h0H, *hpL = p.h0L;
  for (int t=0; t<NT; ++t){
    u16* hoH = (t&1)? p.hH1 : p.hH0;
    u16* hoL = (t&1)? p.hL1 : p.hL0;
    // ---- phase A: z = xW + h@Wzh + ctx@Wzc -> gates -> h,c ----
    {
      int u0 = blk*4;
      int wrow = (l15>>2)*1024 + u0 + (l15&3);
      const u16 *Ah,*Al,*wh,*wl; int kb;
      if (wv < 4){
        Ah = hpH; Al = hpL; kb = wv*256;
        wh = ((t==0)? p.Wr0TH : p.WzhTH) + (size_t)wrow*1024;
        wl = ((t==0)? p.Wr0TL : p.WzhTL) + (size_t)wrow*1024;
      } else {
        Ah = p.ctxH; Al = p.ctxL; kb = (wv-4)*256;
        wh = p.WzcTH + (size_t)wrow*1024;
        wl = p.WzcTL + (size_t)wrow*1024;
      }
      f32x4 acc0 = {}, acc1 = {};
      #pragma unroll
      for (int ki=0; ki<8; ++ki){
        int kl = kb + ki*32 + ko;
        bf16x8 a0h = *(const bf16x8*)(Ah + (size_t)l15*1024 + kl);
        bf16x8 a1h = *(const bf16x8*)(Ah + (size_t)(l15+16)*1024 + kl);
        bf16x8 a0l = *(const bf16x8*)(Al + (size_t)l15*1024 + kl);
        bf16x8 a1l = *(const bf16x8*)(Al + (size_t)(l15+16)*1024 + kl);
        bf16x8 bh = *(const bf16x8*)(wh + kl);
        bf16x8 bl = *(const bf16x8*)(wl + kl);
        acc0 = MFMA(a0h, bl, acc0, 0,0,0);
        acc0 = MFMA(a0l, bh, acc0, 0,0,0);
        acc0 = MFMA(a0h, bh, acc0, 0,0,0);
        acc1 = MFMA(a1h, bl, acc1, 0,0,0);
        acc1 = MFMA(a1l, bh, acc1, 0,0,0);
        acc1 = MFMA(a1h, bh, acc1, 0,0,0);
      }
      #pragma unroll
      for (int r=0; r<4; ++r){
        zs[wv][(lane>>4)*4 + r][l15]      = acc0[r];
        zs[wv][16 + (lane>>4)*4 + r][l15] = acc1[r];
      }
      __syncthreads();
      if (tid < 128){
        int b = tid>>2, du = tid&3;
        const u16* xw = p.xW + (size_t)(b*NT + t)*4096;
        float zg[4];
        #pragma unroll
        for (int g=0; g<4; ++g){
          float v = 0.f;
          #pragma unroll
          for (int w=0; w<8; ++w) v += zs[w][b][g*4+du];
          zg[g] = v + b2f(xw[g*1024 + u0 + du]);
        }
        float i_ = sigm(zg[0]), f_ = sigm(zg[1]), g_ = tanh_(zg[2]), o_ = sigm(zg[3]);
        int ci = b*NU + u0 + du;
        float cn = f_*p.cbuf[ci] + i_*g_;
        p.cbuf[ci] = cn;
        float h = o_*tanh_(cn);
        u16 hi = f2b(h), lo = f2b(h - b2f(hi));
        hoH[ci] = hi; hoL[ci] = lo;
        size_t ho = (size_t)(b*NT + t)*2048 + u0 + du;
        p.hcH[ho] = hi; p.hcL[ho] = lo;
      }
    }
    gbar(p.bar, gen);
    // ---- phase B: q = h@W_q (blocks 0..63) ----
    if (blk < 64){
      int n0 = blk*16;
      const u16* wh = p.WqT + (size_t)(n0+l15)*1024;
      f32x4 acc0 = {}, acc1 = {};
      #pragma unroll
      for (int ki=0; ki<4; ++ki){
        int kk = wv*128 + ki*32 + ko;
        bf16x8 a0h = *(const bf16x8*)(hoH + (size_t)l15*1024 + kk);
        bf16x8 a1h = *(const bf16x8*)(hoH + (size_t)(l15+16)*1024 + kk);
        bf16x8 a0l = *(const bf16x8*)(hoL + (size_t)l15*1024 + kk);
        bf16x8 a1l = *(const bf16x8*)(hoL + (size_t)(l15+16)*1024 + kk);
        bf16x8 bh = *(const bf16x8*)(wh + kk);
        acc0 = MFMA(a0l, bh, acc0, 0,0,0);
        acc0 = MFMA(a0h, bh, acc0, 0,0,0);
        acc1 = MFMA(a1l, bh, acc1, 0,0,0);
        acc1 = MFMA(a1h, bh, acc1, 0,0,0);
      }
      #pragma unroll
      for (int r=0; r<4; ++r){
        zs[wv][(lane>>4)*4 + r][l15]      = acc0[r];
        zs[wv][16 + (lane>>4)*4 + r][l15] = acc1[r];
      }
      __syncthreads();
      {
        int b = tid>>4, c = tid&15;
        float v = 0.f;
        #pragma unroll
        for (int w=0; w<8; ++w) v += zs[w][b][c];
        p.qf[b*NU + n0 + c] = v;
      }
    }
    gbar(p.bar, gen);
    // ---- phase C1: scores ----
    {
      int b = blk>>3, sq = blk&7;
      float qr[16], vr[16];
      #pragma unroll
      for (int j=0; j<4; ++j){
        *(float4*)&qr[j*4] = *(const float4*)(p.qf + b*NU + lane*16 + j*4);
        *(float4*)&vr[j*4] = *(const float4*)(p.v_att + lane*16 + j*4);
      }
      #pragma unroll
      for (int si=0; si<2; ++si){
        int s = sq*16 + wv*2 + si;
        const u16* kp = p.keys + (size_t)(b*128 + s)*1024 + lane*16;
        u16x8 k0 = *(const u16x8*)kp;
        u16x8 k1 = *(const u16x8*)(kp + 8);
        float pv = 0.f;
        #pragma unroll
        for (int j=0; j<8; ++j) pv += vr[j]   * tanh_(b2f(k0[j]) + qr[j]);
        #pragma unroll
        for (int j=0; j<8; ++j) pv += vr[8+j] * tanh_(b2f(k1[j]) + qr[8+j]);
        #pragma unroll
        for (int off=32; off; off>>=1) pv += __shfl_xor(pv, off);
        if (lane==0) p.scf[b*128 + s] = pv;
      }
    }
    gbar(p.bar, gen);
    // ---- phase C2: softmax + ctx ----
    {
      int b = blk>>3, c0 = (blk&7)*128;
      float* alig = smem;
      float* psum = smem + 128;
      if (tid < 64){
        float s0 = p.scf[b*128 + tid], s1 = p.scf[b*128 + 64 + tid];
        float m = fmaxf(s0, s1);
        #pragma unroll
        for (int off=32; off; off>>=1) m = fmaxf(m, __shfl_xor(m, off));
        float e0 = __expf(s0-m), e1 = __expf(s1-m);
        float sum = e0+e1;
        #pragma unroll
        for (int off=32; off; off>>=1) sum += __shfl_xor(sum, off);
        float inv = 1.f/sum;
        alig[tid] = e0*inv; alig[tid+64] = e1*inv;
      }
      __syncthreads();
      {
        int cp = 2*(tid&63), sq8 = tid>>6;
        float ax = 0.f, ay = 0.f;
        #pragma unroll
        for (int si=0; si<16; ++si){
          int s = sq8*16 + si;
          unsigned kv = *(const unsigned*)(p.aB + (size_t)(b*128+s)*1024 + c0 + cp);
          float al = alig[s];
          ax += al*b2f((u16)(kv & 0xffffu));
          ay += al*b2f((u16)(kv >> 16));
        }
        psum[sq8*128 + cp]   = ax;
        psum[sq8*128 + cp+1] = ay;
      }
      __syncthreads();
      if (tid < 128){
        float v = 0.f;
        #pragma unroll
        for (int s8=0; s8<8; ++s8) v += psum[s8*128 + tid];
        int col = c0 + tid, ci = b*NU + col;
        u16 hi = f2b(v), lo = f2b(v - b2f(hi));
        p.ctxH[ci] = hi; p.ctxL[ci] = lo;
        size_t ho = (size_t)(b*NT + t)*2048 + 1024 + col;
        p.hcH[ho] = hi; p.hcL[ho] = lo;
      }
      __syncthreads();
    }
    gbar(p.bar, gen);
    hpH = hoH; hpL = hoL;
  }
}

// ---------------- logits: 128x128-tile, BK=64, double-buffered reg-staged ----------------
#define LDSK 72
__global__ __launch_bounds__(256) void k_logits(
    const u16* __restrict__ A,   // [4096][1024]
    const u16* __restrict__ Bt,  // [32000][1024]
    const float* __restrict__ bias,
    float* __restrict__ C)
{
  __shared__ __align__(16) u16 As[128*LDSK];
  __shared__ __align__(16) u16 Bs[128*LDSK];
  int tid = threadIdx.x, lane = tid&63, wv = tid>>6;
  int m0 = blockIdx.y*128, n0 = blockIdx.x*128;
  int wr = (wv>>1)*64, wc = (wv&1)*64;
  int l15 = lane&15, ko = (lane>>4)*8;
  int srow = tid>>3, sc8 = (tid&7)*8;
  f32x4 acc[4][4] = {};
  uint4 a0[4], b0[4], a1[4], b1[4];

  #define LOADG(ar, br, kk) { \
    _Pragma("unroll") \
    for (int i=0;i<4;++i){ \
      ar[i] = *(const uint4*)(A  + (size_t)(m0+srow+i*32)*1024 + (kk) + sc8); \
      br[i] = *(const uint4*)(Bt + (size_t)(n0+srow+i*32)*1024 + (kk) + sc8); \
    } }
  #define STORES(ar, br) { \
    _Pragma("unroll") \
    for (int i=0;i<4;++i){ \
      *(uint4*)(&As[(srow+i*32)*LDSK + sc8]) = ar[i]; \
      *(uint4*)(&Bs[(srow+i*32)*LDSK + sc8]) = br[i]; \
    } }
  #define COMPUTE() { \
    _Pragma("unroll") \
    for (int ks=0; ks<2; ++ks){ \
      bf16x8 af[4], bf[4]; \
      _Pragma("unroll") \
      for (int i=0;i<4;++i){ \
        af[i] = *(const bf16x8*)(&As[(wr+i*16+l15)*LDSK + ks*32 + ko]); \
        bf[i] = *(const bf16x8*)(&Bs[(wc+i*16+l15)*LDSK + ks*32 + ko]); \
      } \
      _Pragma("unroll") \
      for (int mi=0;mi<4;++mi) \
        _Pragma("unroll") \
        for (int ni=0;ni<4;++ni) \
          acc[mi][ni] = MFMA(af[mi], bf[ni], acc[mi][ni], 0,0,0); \
    } }

  LOADG(a0, b0, 0);
  for (int kk=0; kk<1024; kk+=128){
    __syncthreads();
    STORES(a0, b0);
    if (kk+64 < 1024) LOADG(a1, b1, kk+64);
    __syncthreads();
    COMPUTE();
    __syncthreads();
    STORES(a1, b1);
    if (kk+128 < 1024) LOADG(a0, b0, kk+128);
    __syncthreads();
    COMPUTE();
  }
  #pragma unroll
  for (int mi=0; mi<4; ++mi){
    int row = m0 + wr + mi*16 + (lane>>4)*4;
    #pragma unroll
    for (int ni=0; ni<4; ++ni){
      int col = n0 + wc + ni*16 + l15;
      float bval = bias[col];
      #pragma unroll
      for (int r=0; r<4; ++r){
        if (row + r < NB*NT)
          C[(size_t)(row+r)*NV + col] = acc[mi][ni][r] + bval;
      }
    }
  }
  #undef LOADG
  #undef STORES
  #undef COMPUTE
}

// ---------------- host ----------------
extern "C" void kernel_launch(void* const* d_in, const int* in_sizes, int n_in,
                              void* d_out, int out_size, void* d_ws, size_t ws_size,
                              hipStream_t stream)
{
  (void)in_sizes; (void)n_in; (void)out_size; (void)ws_size;
  const int*   toks  = (const int*)  d_in[0];
  const float* a_in  = (const float*)d_in[1];
  const float* a_tx  = (const float*)d_in[2];
  const float* c_tx  = (const float*)d_in[3];
  const float* emb   = (const float*)d_in[4];
  const float* W_k   = (const float*)d_in[5];
  const float* W_r   = (const float*)d_in[6];
  const float* bvec  = (const float*)d_in[7];
  const float* W_m   = (const float*)d_in[8];
  const float* W_q   = (const float*)d_in[9];
  const float* v_att = (const float*)d_in[10];
  const float* W_a   = (const float*)d_in[11];
  const float* W_o   = (const float*)d_in[12];
  const float* b_o   = (const float*)d_in[13];
  float* out = (float*)d_out;

  char* p = (char*)d_ws;
  auto alloc = [&](size_t bytes)->char*{ char* r = p; p += (bytes + 255) & ~(size_t)255; return r; };

  u16* WzhTH = (u16*)alloc((size_t)4096*1024*2);
  u16* WzhTL = (u16*)alloc((size_t)4096*1024*2);
  u16* WzcTH = (u16*)alloc((size_t)4096*1024*2);
  u16* WzcTL = (u16*)alloc((size_t)4096*1024*2);
  u16* Wr0TH = (u16*)alloc((size_t)4096*1024*2);   // reused as outsH after persist
  u16* Wr0TL = (u16*)alloc((size_t)4096*1024*2);
  u16* WqT   = (u16*)alloc((size_t)1024*1024*2);
  u16* WaTH  = (u16*)alloc((size_t)1024*2048*2);
  u16* WaTL  = (u16*)alloc((size_t)1024*2048*2);
  u16* WmT   = (u16*)alloc((size_t)1024*1024*2);
  u16* WoT   = (u16*)alloc((size_t)NV*1024*2);
  u16* WkxT  = (u16*)alloc((size_t)4096*256*2);
  u16* xB    = (u16*)alloc((size_t)4096*256*2);
  u16* xWb   = (u16*)alloc((size_t)4096*4096*2);
  u16* aB    = (u16*)alloc((size_t)4096*1024*2);
  u16* keysB = (u16*)alloc((size_t)4096*1024*2);
  // union region: prep { WkaT h/l, WaRow h/l, tmpF } -> persist { hcH, hcL }
  char* uni  = alloc((size_t)44*1024*1024);
  u16* WkaTH  = (u16*)uni;
  u16* WkaTL  = WkaTH + (size_t)4096*1024;
  u16* WaRowH = WkaTL + (size_t)4096*1024;
  u16* WaRowL = WaRowH + (size_t)2048*1024;
  float* tmpF = (float*)(WaRowL + (size_t)2048*1024);
  u16* hcH = (u16*)uni;
  u16* hcL = hcH + (size_t)4096*2048;

  u16* h0H  = (u16*)alloc((size_t)NB*NU*2);
  u16* h0L  = (u16*)alloc((size_t)NB*NU*2);
  u16* hH0  = (u16*)alloc((size_t)NB*NU*2);
  u16* hL0  = (u16*)alloc((size_t)NB*NU*2);
  u16* hH1  = (u16*)alloc((size_t)NB*NU*2);
  u16* hL1  = (u16*)alloc((size_t)NB*NU*2);
  u16* ctxH = (u16*)alloc((size_t)NB*NU*2);
  u16* ctxL = (u16*)alloc((size_t)NB*NU*2);
  float* cbuf = (float*)alloc((size_t)NB*NU*4);
  float* qf   = (float*)alloc((size_t)NB*NU*4);
  float* scf  = (float*)alloc((size_t)NB*128*4);
  unsigned* bar = (unsigned*)alloc(256);
  u16* outsH = Wr0TH;   // overlap (Wr0T dead after persistent kernel)

  // ---- init ----
  hipMemsetAsync(bar, 0, 256, stream);
  hipMemsetAsync(ctxH, 0, (size_t)NB*NU*2, stream);
  hipMemsetAsync(ctxL, 0, (size_t)NB*NU*2, stream);
  hipMemcpyAsync(cbuf, c_tx, (size_t)NB*NU*4, hipMemcpyDeviceToDevice, stream);
  k_split<<<128,256,0,stream>>>(a_tx, h0H, h0L, NB*NU);
  k_split<<<2048,256,0,stream>>>(W_a, WaRowH, WaRowL, 2048*1024);
  k_gather<<<(NB*NT*NE)/256,256,0,stream>>>(toks, emb, xB);
  k_conv<<<2048,256,0,stream>>>(a_in, aB, NB*128*NU);

  // ---- weight transposes ----
  k_transpose<<<dim3(128,32),256,0,stream>>>(W_k + (size_t)256*4096, 4096, WkaTH, WkaTL, 1024, 0);
  k_transpose<<<dim3(128,32),256,0,stream>>>(W_r, 4096, Wr0TH, Wr0TL, 1024, 0);
  k_transpose<<<dim3(32,32),256,0,stream>>>(W_q, 1024, WqT, nullptr, 1024, 0);
  k_transpose<<<dim3(32,64),256,0,stream>>>(W_a, 1024, WaTH, WaTL, 2048, 0);
  k_transpose<<<dim3(32,32),256,0,stream>>>(W_m, 1024, WmT, nullptr, 1024, 0);
  k_transpose<<<dim3(1000,32),256,0,stream>>>(W_o, NV, WoT, nullptr, 1024, 0);
  k_transpose<<<dim3(128,8),256,0,stream>>>(W_k, 4096, WkxT, nullptr, 256, 0);

  // ---- precompute GEMMs ----
  // keys = a @ W_m
  k_gemm64<1,0><<<dim3(16,64),256,0,stream>>>(aB, 1024, WmT, 1024, nullptr, keysB, 1024, nullptr, 4096, 1024);
  // xW = x @ W_k[0:256] + b
  k_gemm64<1,1><<<dim3(64,64),256,0,stream>>>(xB, 256, WkxT, 256, nullptr, xWb, 4096, bvec, NB*NT, 256);
  // Wzh = W_r + W_a[0:1024] @ Wk_attn  (3-term split, f32, then transpose+split)
  k_gemm64s<0><<<dim3(64,16),256,0,stream>>>(WaRowH, WaRowL, 1024, WkaTH, WkaTL, 1024,
                                             tmpF, nullptr, 4096, 1024, 1024);
  k_fuseT<<<dim3(128,32),256,0,stream>>>(tmpF, W_r, WzhTH, WzhTL);
  // Wzc = W_a[1024:2048] @ Wk_attn
  k_gemm64s<0><<<dim3(64,16),256,0,stream>>>(WaRowH + (size_t)1024*1024, WaRowL + (size_t)1024*1024, 1024,
                                             WkaTH, WkaTL, 1024, tmpF, nullptr, 4096, 1024, 1024);
  k_fuseT<<<dim3(128,32),256,0,stream>>>(tmpF, nullptr, WzcTH, WzcTL);

  // ---- persistent recurrence ----
  PP pp;
  pp.WzhTH=WzhTH; pp.WzhTL=WzhTL; pp.WzcTH=WzcTH; pp.WzcTL=WzcTL;
  pp.Wr0TH=Wr0TH; pp.Wr0TL=Wr0TL; pp.WqT=WqT; pp.xW=xWb;
  pp.keys=keysB; pp.aB=aB; pp.v_att=v_att;
  pp.h0H=h0H; pp.h0L=h0L;
  pp.hH0=hH0; pp.hL0=hL0; pp.hH1=hH1; pp.hL1=hL1;
  pp.ctxH=ctxH; pp.ctxL=ctxL; pp.cbuf=cbuf; pp.qf=qf; pp.scf=scf;
  pp.hcH=hcH; pp.hcL=hcL; pp.bar=bar;
  k_persist<<<NBLK,512,0,stream>>>(pp);

  // ---- outs = [h|ctx] @ W_a  (3-term split, bf16 out) ----
  k_gemm64s<1><<<dim3(16,64),256,0,stream>>>(hcH, hcL, 2048, WaTH, WaTL, 2048,
                                             nullptr, outsH, 1024, NB*NT, 2048);

  // ---- logits = outs @ W_o + b_o ----
  k_logits<<<dim3(NV/128, 32),256,0,stream>>>(outsH, WoT, b_o, out);
}

// Round 4
// 9141.952 us; speedup vs baseline: 1.2976x; 1.2976x over previous
//
#include <hip/hip_runtime.h>
#include <cstdint>

#define DEVI __device__ __forceinline__

typedef unsigned short u16;
typedef __bf16 bf16x8 __attribute__((ext_vector_type(8)));
typedef u16 u16x8 __attribute__((ext_vector_type(8)));
typedef float f32x4 __attribute__((ext_vector_type(4)));

// B=32, T=128 (127 decode steps), V=32000, E=256, U=AU=M=1024, S=128
#define NB 32
#define NT 127
#define NV 32000
#define NE 256
#define NU 1024
#define NBLK 256

DEVI float b2f(u16 h){ union{unsigned u; float f;} v; v.u = ((unsigned)h)<<16; return v.f; }
DEVI u16 f2b(float f){ union{float f; unsigned u;} v; v.f=f; unsigned u=v.u;
                       return (u16)((u + 0x7fffu + ((u>>16)&1u))>>16); }
DEVI float sigm(float x){ return 1.f/(1.f+__expf(-x)); }
DEVI float tanh_(float x){ return 1.f - 2.f/(1.f+__expf(2.f*x)); }
#define MFMA __builtin_amdgcn_mfma_f32_16x16x32_bf16

// ---------------- small conversion kernels ----------------
__global__ void k_conv(const float* __restrict__ s, u16* __restrict__ d, int n){
  for (int i = blockIdx.x*256 + threadIdx.x; i < n; i += gridDim.x*256) d[i] = f2b(s[i]);
}
__global__ void k_split(const float* __restrict__ s, u16* __restrict__ dh, u16* __restrict__ dl, int n){
  for (int i = blockIdx.x*256 + threadIdx.x; i < n; i += gridDim.x*256){
    float v = s[i]; u16 hi = f2b(v); dh[i]=hi; dl[i]=f2b(v-b2f(hi));
  }
}
__global__ void k_gather(const int* __restrict__ toks, const float* __restrict__ emb, u16* __restrict__ x){
  int i = blockIdx.x*256 + threadIdx.x;
  if (i >= NB*NT*NE) return;
  int bt = i>>8, e = i&255;
  int b = bt/NT, t = bt - b*NT;
  int tok = toks[b*128 + t];                 // dec_in = output_batch[:, :-1]
  x[i] = f2b(emb[(size_t)tok*NE + e]);
}
// transpose f32 (R x C, row stride rs) -> bf16 hi/lo (C x dstStride) at dst[c*dstStride+dstOff+r]
__global__ void k_transpose(const float* __restrict__ src, int rs,
                            u16* __restrict__ dh, u16* __restrict__ dl,
                            int dstStride, int dstOff){
  __shared__ float tile[32][33];
  int tc = blockIdx.x*32, tr = blockIdx.y*32;
  int tx = threadIdx.x & 31, ty = threadIdx.x >> 5;
  #pragma unroll
  for (int rr=0; rr<4; ++rr){
    int r = ty + rr*8;
    tile[r][tx] = src[(size_t)(tr+r)*rs + tc + tx];
  }
  __syncthreads();
  #pragma unroll
  for (int rr=0; rr<4; ++rr){
    int cl = ty + rr*8;
    float v = tile[tx][cl];
    u16 hi = f2b(v);
    size_t o = (size_t)(tc+cl)*dstStride + dstOff + tr + tx;
    dh[o] = hi;
    if (dl) dl[o] = f2b(v - b2f(hi));
  }
}
// transpose+add f32 C[1024][4096] (+addS) -> bf16 hi/lo dst[4096][1024]
__global__ void k_fuseT(const float* __restrict__ C, const float* __restrict__ addS,
                        u16* __restrict__ dh, u16* __restrict__ dl){
  __shared__ float tile[32][33];
  int tc = blockIdx.x*32, tr = blockIdx.y*32;
  int tx = threadIdx.x & 31, ty = threadIdx.x >> 5;
  #pragma unroll
  for (int rr=0; rr<4; ++rr){
    int r = ty + rr*8;
    float v = C[(size_t)(tr+r)*4096 + tc + tx];
    if (addS) v += addS[(size_t)(tr+r)*4096 + tc + tx];
    tile[r][tx] = v;
  }
  __syncthreads();
  #pragma unroll
  for (int rr=0; rr<4; ++rr){
    int cl = ty + rr*8;
    float v = tile[tx][cl];
    u16 hi = f2b(v);
    size_t o = (size_t)(tc+cl)*1024 + tr + tx;
    dh[o] = hi; dl[o] = f2b(v - b2f(hi));
  }
}

// ---------------- generic 64x64-tile bf16 MFMA GEMM (single-term) ----------------
template<int OUTF, int BIAS>
__global__ __launch_bounds__(256) void k_gemm64(
    const u16* __restrict__ A, int lda,
    const u16* __restrict__ Bt, int ldb,
    float* __restrict__ Cf, u16* __restrict__ Cb, int ldc,
    const float* __restrict__ bias, int M, int K)
{
  __shared__ __align__(16) u16 As[64][40];
  __shared__ __align__(16) u16 Bs[64][40];
  int n0 = blockIdx.x*64, m0 = blockIdx.y*64;
  int tid = threadIdx.x, lane = tid & 63, w = tid>>6;
  int lr = tid>>2, lk = (tid&3)*8;
  f32x4 acc[4] = {};
  for (int kk=0; kk<K; kk+=32){
    uint4 av = make_uint4(0,0,0,0);
    int row = m0 + lr;
    if (row < M) av = *(const uint4*)(A + (size_t)row*lda + kk + lk);
    *(uint4*)(&As[lr][lk]) = av;
    uint4 bv = *(const uint4*)(Bt + (size_t)(n0+lr)*ldb + kk + lk);
    *(uint4*)(&Bs[lr][lk]) = bv;
    __syncthreads();
    bf16x8 af = *(const bf16x8*)(&As[w*16 + (lane&15)][(lane>>4)*8]);
    #pragma unroll
    for (int ni=0; ni<4; ++ni){
      bf16x8 bfr = *(const bf16x8*)(&Bs[ni*16 + (lane&15)][(lane>>4)*8]);
      acc[ni] = MFMA(af, bfr, acc[ni], 0,0,0);
    }
    __syncthreads();
  }
  #pragma unroll
  for (int ni=0; ni<4; ++ni){
    #pragma unroll
    for (int r=0; r<4; ++r){
      int row = m0 + w*16 + (lane>>4)*4 + r;
      int col = n0 + ni*16 + (lane&15);
      if (row < M){
        float v = acc[ni][r];
        if (BIAS) v += bias[col];
        if (OUTF==0) Cf[(size_t)row*ldc + col] = v;
        else         Cb[(size_t)row*ldc + col] = f2b(v);
      }
    }
  }
}

// ---------------- 3-term split-precision 64x64 GEMM: (Ah+Al) x (Bh+Bl) ----------------
template<int OUTF>
__global__ __launch_bounds__(256) void k_gemm64s(
    const u16* __restrict__ Ah, const u16* __restrict__ Al, int lda,
    const u16* __restrict__ Bh, const u16* __restrict__ Bl, int ldb,
    float* __restrict__ Cf, u16* __restrict__ Cb, int ldc, int M, int K)
{
  __shared__ __align__(16) u16 Ash[64][40], Asl[64][40], Bsh[64][40], Bsl[64][40];
  int n0 = blockIdx.x*64, m0 = blockIdx.y*64;
  int tid = threadIdx.x, lane = tid & 63, w = tid>>6;
  int lr = tid>>2, lk = (tid&3)*8;
  f32x4 acc[4] = {};
  for (int kk=0; kk<K; kk+=32){
    uint4 avh = make_uint4(0,0,0,0), avl = make_uint4(0,0,0,0);
    int row = m0 + lr;
    if (row < M){
      avh = *(const uint4*)(Ah + (size_t)row*lda + kk + lk);
      avl = *(const uint4*)(Al + (size_t)row*lda + kk + lk);
    }
    *(uint4*)(&Ash[lr][lk]) = avh;
    *(uint4*)(&Asl[lr][lk]) = avl;
    *(uint4*)(&Bsh[lr][lk]) = *(const uint4*)(Bh + (size_t)(n0+lr)*ldb + kk + lk);
    *(uint4*)(&Bsl[lr][lk]) = *(const uint4*)(Bl + (size_t)(n0+lr)*ldb + kk + lk);
    __syncthreads();
    bf16x8 afh = *(const bf16x8*)(&Ash[w*16 + (lane&15)][(lane>>4)*8]);
    bf16x8 afl = *(const bf16x8*)(&Asl[w*16 + (lane&15)][(lane>>4)*8]);
    #pragma unroll
    for (int ni=0; ni<4; ++ni){
      bf16x8 bfh = *(const bf16x8*)(&Bsh[ni*16 + (lane&15)][(lane>>4)*8]);
      bf16x8 bfl = *(const bf16x8*)(&Bsl[ni*16 + (lane&15)][(lane>>4)*8]);
      acc[ni] = MFMA(afh, bfl, acc[ni], 0,0,0);
      acc[ni] = MFMA(afl, bfh, acc[ni], 0,0,0);
      acc[ni] = MFMA(afh, bfh, acc[ni], 0,0,0);
    }
    __syncthreads();
  }
  #pragma unroll
  for (int ni=0; ni<4; ++ni){
    #pragma unroll
    for (int r=0; r<4; ++r){
      int row = m0 + w*16 + (lane>>4)*4 + r;
      int col = n0 + ni*16 + (lane&15);
      if (row < M){
        float v = acc[ni][r];
        if (OUTF==0) Cf[(size_t)row*ldc + col] = v;
        else         Cb[(size_t)row*ldc + col] = f2b(v);
      }
    }
  }
}

// ---------------- persistent recurrence kernel ----------------
struct PP {
  const u16 *WzhTH, *WzhTL;   // [4096][1024]
  const u16 *WzcTH, *WzcTL;   // [4096][1024]
  const u16 *Wr0TH, *Wr0TL;   // [4096][1024] (t=0 h-weight = W_r^T)
  const u16 *WqT;             // [1024][1024]
  const u16 *xW;              // rows b*NT+t, 4096 cols (bf16, bias folded)
  const u16 *keys;            // [4096][1024]
  const u16 *aB;              // [4096][1024]
  const float *v_att;         // [1024]
  const u16 *h0H, *h0L;       // [32][1024]
  u16 *hH0,*hL0,*hH1,*hL1;    // ping-pong h
  u16 *ctxH, *ctxL;           // [32][1024] (zero-init)
  float *cbuf;                // [32][1024] (init c_tx)
  float *qf;                  // [32][1024]
  float *scf;                 // [32][128]
  u16 *hcH, *hcL;             // [4096][2048] hist [h | ctx]
  unsigned *bar;
};

// two-level barrier: 16 groups x 16 blocks (separate cachelines) -> master
DEVI void gbar(unsigned* bars, unsigned gen){
  __syncthreads();
  if (threadIdx.x == 0){
    unsigned* grp = bars + (blockIdx.x & 15)*32;
    unsigned* mst = bars + 512;
    unsigned v = __hip_atomic_fetch_add(grp, 1u, __ATOMIC_ACQ_REL, __HIP_MEMORY_SCOPE_AGENT);
    if (v + 1u == gen*16u)
      __hip_atomic_fetch_add(mst, 1u, __ATOMIC_ACQ_REL, __HIP_MEMORY_SCOPE_AGENT);
    while (__hip_atomic_load(mst, __ATOMIC_RELAXED, __HIP_MEMORY_SCOPE_AGENT) < gen*16u)
      __builtin_amdgcn_s_sleep(1);
    __builtin_amdgcn_fence(__ATOMIC_ACQUIRE, "agent");
  }
  __syncthreads();
}

__global__ __launch_bounds__(512,1) void k_persist(PP p){
  __shared__ float smem[4096];   // 16 KB: zs[8][32][16] / alig[128]+psum[8][128]
  float (*zs)[32][16] = (float(*)[32][16])smem;
  int tid = threadIdx.x, lane = tid&63, wv = tid>>6, blk = blockIdx.x;
  int l15 = lane&15, ko = (lane>>4)*8;

  // ================= register preloads (fence-proof residency) =================
  // phase-A weight slice: 16 rows (4 gates x 4 u's), this wave's 256-k window
  int u0 = blk*4;
  int wrow = (l15>>2)*1024 + u0 + (l15&3);
  size_t woff = (size_t)wrow*1024 + (wv&3)*256 + ko;
  const u16 *whG = (wv<4 ? p.Wr0TH : p.WzcTH) + woff;
  const u16 *wlG = (wv<4 ? p.Wr0TL : p.WzcTL) + woff;
  bf16x8 wH[8], wL[8];
  #pragma unroll
  for (int ki=0; ki<8; ++ki){
    wH[ki] = *(const bf16x8*)(whG + ki*32);
    wL[ki] = *(const bf16x8*)(wlG + ki*32);
  }
  // phase-B Wq slice (blocks 0..63 only)
  bf16x8 wq[4];
  int nq0 = (blk&63)*16;
  if (blk < 64){
    const u16* qg = p.WqT + (size_t)(nq0+l15)*1024 + wv*128 + ko;
    #pragma unroll
    for (int ki=0; ki<4; ++ki) wq[ki] = *(const bf16x8*)(qg + ki*32);
  }
  // phase-C1 keys slice: block (b=blk>>3, sq=blk&7), wave rows sq*16+wv*2+{0,1}
  int cb = blk>>3, sq = blk&7;
  u16x8 kr[2][2];
  #pragma unroll
  for (int si=0; si<2; ++si){
    const u16* kp = p.keys + (size_t)(cb*128 + sq*16 + wv*2 + si)*1024 + lane*16;
    kr[si][0] = *(const u16x8*)kp;
    kr[si][1] = *(const u16x8*)(kp + 8);
  }
  // phase-C2 aB slice: block (b=cb, c0), thread (sq8=tid>>6, cp=2*(tid&63))
  int c0 = (blk&7)*128, cp = 2*(tid&63), sq8 = tid>>6;
  unsigned av[16];
  #pragma unroll
  for (int si=0; si<16; ++si)
    av[si] = *(const unsigned*)(p.aB + (size_t)(cb*128 + sq8*16 + si)*1024 + c0 + cp);

  unsigned gen = 0;
  const u16 *hpH = p.h0H, *hpL = p.h0L;
  for (int t=0; t<NT; ++t){
    u16* hoH = (t&1)? p.hH1 : p.hH0;
    u16* hoL = (t&1)? p.hL1 : p.hL0;
    // ---- phase A: z = xW + h@Wzh + ctx@Wzc -> gates -> h,c ----
    {
      const u16 *Ah = (wv<4)? hpH : p.ctxH;
      const u16 *Al = (wv<4)? hpL : p.ctxL;
      int kb = (wv&3)*256;
      f32x4 acc0 = {}, acc1 = {};
      #pragma unroll
      for (int ki=0; ki<8; ++ki){
        int kl = kb + ki*32 + ko;
        bf16x8 a0h = *(const bf16x8*)(Ah + (size_t)l15*1024 + kl);
        bf16x8 a1h = *(const bf16x8*)(Ah + (size_t)(l15+16)*1024 + kl);
        bf16x8 a0l = *(const bf16x8*)(Al + (size_t)l15*1024 + kl);
        bf16x8 a1l = *(const bf16x8*)(Al + (size_t)(l15+16)*1024 + kl);
        acc0 = MFMA(a0h, wL[ki], acc0, 0,0,0);
        acc0 = MFMA(a0l, wH[ki], acc0, 0,0,0);
        acc0 = MFMA(a0h, wH[ki], acc0, 0,0,0);
        acc1 = MFMA(a1h, wL[ki], acc1, 0,0,0);
        acc1 = MFMA(a1l, wH[ki], acc1, 0,0,0);
        acc1 = MFMA(a1h, wH[ki], acc1, 0,0,0);
      }
      // after t=0 consumed Wr0, swap in the steady-state Wzh (hidden by B/C phases)
      if (t == 0 && wv < 4){
        const u16* nh = p.WzhTH + woff;
        const u16* nl = p.WzhTL + woff;
        #pragma unroll
        for (int ki=0; ki<8; ++ki){
          wH[ki] = *(const bf16x8*)(nh + ki*32);
          wL[ki] = *(const bf16x8*)(nl + ki*32);
        }
      }
      #pragma unroll
      for (int r=0; r<4; ++r){
        zs[wv][(lane>>4)*4 + r][l15]      = acc0[r];
        zs[wv][16 + (lane>>4)*4 + r][l15] = acc1[r];
      }
      __syncthreads();
      if (tid < 128){
        int b = tid>>2, du = tid&3;
        const u16* xw = p.xW + (size_t)(b*NT + t)*4096;
        float zg[4];
        #pragma unroll
        for (int g=0; g<4; ++g){
          float v = 0.f;
          #pragma unroll
          for (int w=0; w<8; ++w) v += zs[w][b][g*4+du];
          zg[g] = v + b2f(xw[g*1024 + u0 + du]);
        }
        float i_ = sigm(zg[0]), f_ = sigm(zg[1]), g_ = tanh_(zg[2]), o_ = sigm(zg[3]);
        int ci = b*NU + u0 + du;
        float cn = f_*p.cbuf[ci] + i_*g_;
        p.cbuf[ci] = cn;
        float h = o_*tanh_(cn);
        u16 hi = f2b(h), lo = f2b(h - b2f(hi));
        hoH[ci] = hi; hoL[ci] = lo;
        size_t ho = (size_t)(b*NT + t)*2048 + u0 + du;
        p.hcH[ho] = hi; p.hcL[ho] = lo;
      }
    }
    ++gen; gbar(p.bar, gen);
    // ---- phase B: q = h@W_q (blocks 0..63) ----
    if (blk < 64){
      f32x4 acc0 = {}, acc1 = {};
      #pragma unroll
      for (int ki=0; ki<4; ++ki){
        int kk = wv*128 + ki*32 + ko;
        bf16x8 a0h = *(const bf16x8*)(hoH + (size_t)l15*1024 + kk);
        bf16x8 a1h = *(const bf16x8*)(hoH + (size_t)(l15+16)*1024 + kk);
        bf16x8 a0l = *(const bf16x8*)(hoL + (size_t)l15*1024 + kk);
        bf16x8 a1l = *(const bf16x8*)(hoL + (size_t)(l15+16)*1024 + kk);
        acc0 = MFMA(a0l, wq[ki], acc0, 0,0,0);
        acc0 = MFMA(a0h, wq[ki], acc0, 0,0,0);
        acc1 = MFMA(a1l, wq[ki], acc1, 0,0,0);
        acc1 = MFMA(a1h, wq[ki], acc1, 0,0,0);
      }
      #pragma unroll
      for (int r=0; r<4; ++r){
        zs[wv][(lane>>4)*4 + r][l15]      = acc0[r];
        zs[wv][16 + (lane>>4)*4 + r][l15] = acc1[r];
      }
      __syncthreads();
      {
        int b = tid>>4, c = tid&15;
        float v = 0.f;
        #pragma unroll
        for (int w=0; w<8; ++w) v += zs[w][b][c];
        p.qf[b*NU + nq0 + c] = v;
      }
    }
    ++gen; gbar(p.bar, gen);
    // ---- phase C1: scores (keys in registers) ----
    {
      float qr[16], vr[16];
      #pragma unroll
      for (int j=0; j<4; ++j){
        *(float4*)&qr[j*4] = *(const float4*)(p.qf + cb*NU + lane*16 + j*4);
        *(float4*)&vr[j*4] = *(const float4*)(p.v_att + lane*16 + j*4);
      }
      #pragma unroll
      for (int si=0; si<2; ++si){
        float pv = 0.f;
        #pragma unroll
        for (int j=0; j<8; ++j) pv += vr[j]   * tanh_(b2f(kr[si][0][j]) + qr[j]);
        #pragma unroll
        for (int j=0; j<8; ++j) pv += vr[8+j] * tanh_(b2f(kr[si][1][j]) + qr[8+j]);
        #pragma unroll
        for (int off=32; off; off>>=1) pv += __shfl_xor(pv, off);
        if (lane==0) p.scf[cb*128 + sq*16 + wv*2 + si] = pv;
      }
    }
    ++gen; gbar(p.bar, gen);
    // ---- phase C2: softmax + ctx (aB in registers) ----
    {
      float* alig = smem;
      float* psum = smem + 128;
      if (tid < 64){
        float s0 = p.scf[cb*128 + tid], s1 = p.scf[cb*128 + 64 + tid];
        float m = fmaxf(s0, s1);
        #pragma unroll
        for (int off=32; off; off>>=1) m = fmaxf(m, __shfl_xor(m, off));
        float e0 = __expf(s0-m), e1 = __expf(s1-m);
        float sum = e0+e1;
        #pragma unroll
        for (int off=32; off; off>>=1) sum += __shfl_xor(sum, off);
        float inv = 1.f/sum;
        alig[tid] = e0*inv; alig[tid+64] = e1*inv;
      }
      __syncthreads();
      {
        float ax = 0.f, ay = 0.f;
        #pragma unroll
        for (int si=0; si<16; ++si){
          unsigned kv = av[si];
          float al = alig[sq8*16 + si];
          ax += al*b2f((u16)(kv & 0xffffu));
          ay += al*b2f((u16)(kv >> 16));
        }
        psum[sq8*128 + cp]   = ax;
        psum[sq8*128 + cp+1] = ay;
      }
      __syncthreads();
      if (tid < 128){
        float v = 0.f;
        #pragma unroll
        for (int s8=0; s8<8; ++s8) v += psum[s8*128 + tid];
        int col = c0 + tid, ci = cb*NU + col;
        u16 hi = f2b(v), lo = f2b(v - b2f(hi));
        p.ctxH[ci] = hi; p.ctxL[ci] = lo;
        size_t ho = (size_t)(cb*NT + t)*2048 + 1024 + col;
        p.hcH[ho] = hi; p.hcL[ho] = lo;
      }
      __syncthreads();
    }
    ++gen; gbar(p.bar, gen);
    hpH = hoH; hpL = hoL;
  }
}

// ---------------- logits: 128x128-tile, BK=64, double-buffered reg-staged ----------------
#define LDSK 72
__global__ __launch_bounds__(256) void k_logits(
    const u16* __restrict__ A,   // [4096][1024]
    const u16* __restrict__ Bt,  // [32000][1024]
    const float* __restrict__ bias,
    float* __restrict__ C)
{
  __shared__ __align__(16) u16 As[128*LDSK];
  __shared__ __align__(16) u16 Bs[128*LDSK];
  int tid = threadIdx.x, lane = tid&63, wv = tid>>6;
  int m0 = blockIdx.y*128, n0 = blockIdx.x*128;
  int wr = (wv>>1)*64, wc = (wv&1)*64;
  int l15 = lane&15, ko = (lane>>4)*8;
  int srow = tid>>3, sc8 = (tid&7)*8;
  f32x4 acc[4][4] = {};
  uint4 a0[4], b0[4], a1[4], b1[4];

  #define LOADG(ar, br, kk) { \
    _Pragma("unroll") \
    for (int i=0;i<4;++i){ \
      ar[i] = *(const uint4*)(A  + (size_t)(m0+srow+i*32)*1024 + (kk) + sc8); \
      br[i] = *(const uint4*)(Bt + (size_t)(n0+srow+i*32)*1024 + (kk) + sc8); \
    } }
  #define STORES(ar, br) { \
    _Pragma("unroll") \
    for (int i=0;i<4;++i){ \
      *(uint4*)(&As[(srow+i*32)*LDSK + sc8]) = ar[i]; \
      *(uint4*)(&Bs[(srow+i*32)*LDSK + sc8]) = br[i]; \
    } }
  #define COMPUTE() { \
    _Pragma("unroll") \
    for (int ks=0; ks<2; ++ks){ \
      bf16x8 af[4], bf[4]; \
      _Pragma("unroll") \
      for (int i=0;i<4;++i){ \
        af[i] = *(const bf16x8*)(&As[(wr+i*16+l15)*LDSK + ks*32 + ko]); \
        bf[i] = *(const bf16x8*)(&Bs[(wc+i*16+l15)*LDSK + ks*32 + ko]); \
      } \
      _Pragma("unroll") \
      for (int mi=0;mi<4;++mi) \
        _Pragma("unroll") \
        for (int ni=0;ni<4;++ni) \
          acc[mi][ni] = MFMA(af[mi], bf[ni], acc[mi][ni], 0,0,0); \
    } }

  LOADG(a0, b0, 0);
  for (int kk=0; kk<1024; kk+=128){
    __syncthreads();
    STORES(a0, b0);
    if (kk+64 < 1024) LOADG(a1, b1, kk+64);
    __syncthreads();
    COMPUTE();
    __syncthreads();
    STORES(a1, b1);
    if (kk+128 < 1024) LOADG(a0, b0, kk+128);
    __syncthreads();
    COMPUTE();
  }
  #pragma unroll
  for (int mi=0; mi<4; ++mi){
    int row = m0 + wr + mi*16 + (lane>>4)*4;
    #pragma unroll
    for (int ni=0; ni<4; ++ni){
      int col = n0 + wc + ni*16 + l15;
      float bval = bias[col];
      #pragma unroll
      for (int r=0; r<4; ++r){
        if (row + r < NB*NT)
          C[(size_t)(row+r)*NV + col] = acc[mi][ni][r] + bval;
      }
    }
  }
  #undef LOADG
  #undef STORES
  #undef COMPUTE
}

// ---------------- host ----------------
extern "C" void kernel_launch(void* const* d_in, const int* in_sizes, int n_in,
                              void* d_out, int out_size, void* d_ws, size_t ws_size,
                              hipStream_t stream)
{
  (void)in_sizes; (void)n_in; (void)out_size; (void)ws_size;
  const int*   toks  = (const int*)  d_in[0];
  const float* a_in  = (const float*)d_in[1];
  const float* a_tx  = (const float*)d_in[2];
  const float* c_tx  = (const float*)d_in[3];
  const float* emb   = (const float*)d_in[4];
  const float* W_k   = (const float*)d_in[5];
  const float* W_r   = (const float*)d_in[6];
  const float* bvec  = (const float*)d_in[7];
  const float* W_m   = (const float*)d_in[8];
  const float* W_q   = (const float*)d_in[9];
  const float* v_att = (const float*)d_in[10];
  const float* W_a   = (const float*)d_in[11];
  const float* W_o   = (const float*)d_in[12];
  const float* b_o   = (const float*)d_in[13];
  float* out = (float*)d_out;

  char* p = (char*)d_ws;
  auto alloc = [&](size_t bytes)->char*{ char* r = p; p += (bytes + 255) & ~(size_t)255; return r; };

  u16* WzhTH = (u16*)alloc((size_t)4096*1024*2);
  u16* WzhTL = (u16*)alloc((size_t)4096*1024*2);
  u16* WzcTH = (u16*)alloc((size_t)4096*1024*2);
  u16* WzcTL = (u16*)alloc((size_t)4096*1024*2);
  u16* Wr0TH = (u16*)alloc((size_t)4096*1024*2);   // reused as outsH after persist
  u16* Wr0TL = (u16*)alloc((size_t)4096*1024*2);
  u16* WqT   = (u16*)alloc((size_t)1024*1024*2);
  u16* WaTH  = (u16*)alloc((size_t)1024*2048*2);
  u16* WaTL  = (u16*)alloc((size_t)1024*2048*2);
  u16* WmT   = (u16*)alloc((size_t)1024*1024*2);
  u16* WoT   = (u16*)alloc((size_t)NV*1024*2);
  u16* WkxT  = (u16*)alloc((size_t)4096*256*2);
  u16* xB    = (u16*)alloc((size_t)4096*256*2);
  u16* xWb   = (u16*)alloc((size_t)4096*4096*2);
  u16* aB    = (u16*)alloc((size_t)4096*1024*2);
  u16* keysB = (u16*)alloc((size_t)4096*1024*2);
  // union region: prep { WkaT h/l, WaRow h/l, tmpF } -> persist { hcH, hcL }
  char* uni  = alloc((size_t)44*1024*1024);
  u16* WkaTH  = (u16*)uni;
  u16* WkaTL  = WkaTH + (size_t)4096*1024;
  u16* WaRowH = WkaTL + (size_t)4096*1024;
  u16* WaRowL = WaRowH + (size_t)2048*1024;
  float* tmpF = (float*)(WaRowL + (size_t)2048*1024);
  u16* hcH = (u16*)uni;
  u16* hcL = hcH + (size_t)4096*2048;

  u16* h0H  = (u16*)alloc((size_t)NB*NU*2);
  u16* h0L  = (u16*)alloc((size_t)NB*NU*2);
  u16* hH0  = (u16*)alloc((size_t)NB*NU*2);
  u16* hL0  = (u16*)alloc((size_t)NB*NU*2);
  u16* hH1  = (u16*)alloc((size_t)NB*NU*2);
  u16* hL1  = (u16*)alloc((size_t)NB*NU*2);
  u16* ctxH = (u16*)alloc((size_t)NB*NU*2);
  u16* ctxL = (u16*)alloc((size_t)NB*NU*2);
  float* cbuf = (float*)alloc((size_t)NB*NU*4);
  float* qf   = (float*)alloc((size_t)NB*NU*4);
  float* scf  = (float*)alloc((size_t)NB*128*4);
  unsigned* bar = (unsigned*)alloc(4096);
  u16* outsH = Wr0TH;   // overlap (Wr0T dead after persistent kernel)

  // ---- init ----
  hipMemsetAsync(bar, 0, 4096, stream);
  hipMemsetAsync(ctxH, 0, (size_t)NB*NU*2, stream);
  hipMemsetAsync(ctxL, 0, (size_t)NB*NU*2, stream);
  hipMemcpyAsync(cbuf, c_tx, (size_t)NB*NU*4, hipMemcpyDeviceToDevice, stream);
  k_split<<<128,256,0,stream>>>(a_tx, h0H, h0L, NB*NU);
  k_split<<<2048,256,0,stream>>>(W_a, WaRowH, WaRowL, 2048*1024);
  k_gather<<<(NB*NT*NE)/256,256,0,stream>>>(toks, emb, xB);
  k_conv<<<2048,256,0,stream>>>(a_in, aB, NB*128*NU);

  // ---- weight transposes ----
  k_transpose<<<dim3(128,32),256,0,stream>>>(W_k + (size_t)256*4096, 4096, WkaTH, WkaTL, 1024, 0);
  k_transpose<<<dim3(128,32),256,0,stream>>>(W_r, 4096, Wr0TH, Wr0TL, 1024, 0);
  k_transpose<<<dim3(32,32),256,0,stream>>>(W_q, 1024, WqT, nullptr, 1024, 0);
  k_transpose<<<dim3(32,64),256,0,stream>>>(W_a, 1024, WaTH, WaTL, 2048, 0);
  k_transpose<<<dim3(32,32),256,0,stream>>>(W_m, 1024, WmT, nullptr, 1024, 0);
  k_transpose<<<dim3(1000,32),256,0,stream>>>(W_o, NV, WoT, nullptr, 1024, 0);
  k_transpose<<<dim3(128,8),256,0,stream>>>(W_k, 4096, WkxT, nullptr, 256, 0);

  // ---- precompute GEMMs ----
  // keys = a @ W_m
  k_gemm64<1,0><<<dim3(16,64),256,0,stream>>>(aB, 1024, WmT, 1024, nullptr, keysB, 1024, nullptr, 4096, 1024);
  // xW = x @ W_k[0:256] + b
  k_gemm64<1,1><<<dim3(64,64),256,0,stream>>>(xB, 256, WkxT, 256, nullptr, xWb, 4096, bvec, NB*NT, 256);
  // Wzh = W_r + W_a[0:1024] @ Wk_attn  (3-term split, f32, then transpose+split)
  k_gemm64s<0><<<dim3(64,16),256,0,stream>>>(WaRowH, WaRowL, 1024, WkaTH, WkaTL, 1024,
                                             tmpF, nullptr, 4096, 1024, 1024);
  k_fuseT<<<dim3(128,32),256,0,stream>>>(tmpF, W_r, WzhTH, WzhTL);
  // Wzc = W_a[1024:2048] @ Wk_attn
  k_gemm64s<0><<<dim3(64,16),256,0,stream>>>(WaRowH + (size_t)1024*1024, WaRowL + (size_t)1024*1024, 1024,
                                             WkaTH, WkaTL, 1024, tmpF, nullptr, 4096, 1024, 1024);
  k_fuseT<<<dim3(128,32),256,0,stream>>>(tmpF, nullptr, WzcTH, WzcTL);

  // ---- persistent recurrence ----
  PP pp;
  pp.WzhTH=WzhTH; pp.WzhTL=WzhTL; pp.WzcTH=WzcTH; pp.WzcTL=WzcTL;
  pp.Wr0TH=Wr0TH; pp.Wr0TL=Wr0TL; pp.WqT=WqT; pp.xW=xWb;
  pp.keys=keysB; pp.aB=aB; pp.v_att=v_att;
  pp.h0H=h0H; pp.h0L=h0L;
  pp.hH0=hH0; pp.hL0=hL0; pp.hH1=hH1; pp.hL1=hL1;
  pp.ctxH=ctxH; pp.ctxL=ctxL; pp.cbuf=cbuf; pp.qf=qf; pp.scf=scf;
  pp.hcH=hcH; pp.hcL=hcL; pp.bar=bar;
  k_persist<<<NBLK,512,0,stream>>>(pp);

  // ---- outs = [h|ctx] @ W_a  (3-term split, bf16 out) ----
  k_gemm64s<1><<<dim3(16,64),256,0,stream>>>(hcH, hcL, 2048, WaTH, WaTL, 2048,
                                             nullptr, outsH, 1024, NB*NT, 2048);

  // ---- logits = outs @ W_o + b_o ----
  k_logits<<<dim3(NV/128, 32),256,0,stream>>>(outsH, WoT, b_o, out);
}

// Round 5
// 8546.835 us; speedup vs baseline: 1.3880x; 1.0696x over previous
//
#include <hip/hip_runtime.h>
#include <cstdint>

#define DEVI __device__ __forceinline__

typedef unsigned short u16;
typedef __bf16 bf16x8 __attribute__((ext_vector_type(8)));
typedef u16 u16x8 __attribute__((ext_vector_type(8)));
typedef float f32x4 __attribute__((ext_vector_type(4)));

// B=32, T=128 (127 decode steps), V=32000, E=256, U=AU=M=1024, S=128
#define NB 32
#define NT 127
#define NV 32000
#define NE 256
#define NU 1024
#define NBLK 256

DEVI float b2f(u16 h){ union{unsigned u; float f;} v; v.u = ((unsigned)h)<<16; return v.f; }
DEVI u16 f2b(float f){ union{float f; unsigned u;} v; v.f=f; unsigned u=v.u;
                       return (u16)((u + 0x7fffu + ((u>>16)&1u))>>16); }
DEVI float sigm(float x){ return 1.f/(1.f+__expf(-x)); }
DEVI float tanh_(float x){ return 1.f - 2.f/(1.f+__expf(2.f*x)); }
#define MFMA __builtin_amdgcn_mfma_f32_16x16x32_bf16

// ---------------- small conversion kernels ----------------
__global__ void k_conv(const float* __restrict__ s, u16* __restrict__ d, int n){
  for (int i = blockIdx.x*256 + threadIdx.x; i < n; i += gridDim.x*256) d[i] = f2b(s[i]);
}
__global__ void k_split(const float* __restrict__ s, u16* __restrict__ dh, u16* __restrict__ dl, int n){
  for (int i = blockIdx.x*256 + threadIdx.x; i < n; i += gridDim.x*256){
    float v = s[i]; u16 hi = f2b(v); dh[i]=hi; dl[i]=f2b(v-b2f(hi));
  }
}
__global__ void k_gather(const int* __restrict__ toks, const float* __restrict__ emb, u16* __restrict__ x){
  int i = blockIdx.x*256 + threadIdx.x;
  if (i >= NB*NT*NE) return;
  int bt = i>>8, e = i&255;
  int b = bt/NT, t = bt - b*NT;
  int tok = toks[b*128 + t];                 // dec_in = output_batch[:, :-1]
  x[i] = f2b(emb[(size_t)tok*NE + e]);
}
// transpose f32 (R x C, row stride rs) -> bf16 hi/lo (C x dstStride) at dst[c*dstStride+dstOff+r]
__global__ void k_transpose(const float* __restrict__ src, int rs,
                            u16* __restrict__ dh, u16* __restrict__ dl,
                            int dstStride, int dstOff){
  __shared__ float tile[32][33];
  int tc = blockIdx.x*32, tr = blockIdx.y*32;
  int tx = threadIdx.x & 31, ty = threadIdx.x >> 5;
  #pragma unroll
  for (int rr=0; rr<4; ++rr){
    int r = ty + rr*8;
    tile[r][tx] = src[(size_t)(tr+r)*rs + tc + tx];
  }
  __syncthreads();
  #pragma unroll
  for (int rr=0; rr<4; ++rr){
    int cl = ty + rr*8;
    float v = tile[tx][cl];
    u16 hi = f2b(v);
    size_t o = (size_t)(tc+cl)*dstStride + dstOff + tr + tx;
    dh[o] = hi;
    if (dl) dl[o] = f2b(v - b2f(hi));
  }
}
// transpose+add f32 C[1024][4096] (+addS) -> bf16 hi/lo dst[4096][1024]
__global__ void k_fuseT(const float* __restrict__ C, const float* __restrict__ addS,
                        u16* __restrict__ dh, u16* __restrict__ dl){
  __shared__ float tile[32][33];
  int tc = blockIdx.x*32, tr = blockIdx.y*32;
  int tx = threadIdx.x & 31, ty = threadIdx.x >> 5;
  #pragma unroll
  for (int rr=0; rr<4; ++rr){
    int r = ty + rr*8;
    float v = C[(size_t)(tr+r)*4096 + tc + tx];
    if (addS) v += addS[(size_t)(tr+r)*4096 + tc + tx];
    tile[r][tx] = v;
  }
  __syncthreads();
  #pragma unroll
  for (int rr=0; rr<4; ++rr){
    int cl = ty + rr*8;
    float v = tile[tx][cl];
    u16 hi = f2b(v);
    size_t o = (size_t)(tc+cl)*1024 + tr + tx;
    dh[o] = hi; dl[o] = f2b(v - b2f(hi));
  }
}

// ---------------- generic 64x64-tile bf16 MFMA GEMM (single-term) ----------------
template<int OUTF, int BIAS>
__global__ __launch_bounds__(256) void k_gemm64(
    const u16* __restrict__ A, int lda,
    const u16* __restrict__ Bt, int ldb,
    float* __restrict__ Cf, u16* __restrict__ Cb, int ldc,
    const float* __restrict__ bias, int M, int K)
{
  __shared__ __align__(16) u16 As[64][40];
  __shared__ __align__(16) u16 Bs[64][40];
  int n0 = blockIdx.x*64, m0 = blockIdx.y*64;
  int tid = threadIdx.x, lane = tid & 63, w = tid>>6;
  int lr = tid>>2, lk = (tid&3)*8;
  f32x4 acc[4] = {};
  for (int kk=0; kk<K; kk+=32){
    uint4 av = make_uint4(0,0,0,0);
    int row = m0 + lr;
    if (row < M) av = *(const uint4*)(A + (size_t)row*lda + kk + lk);
    *(uint4*)(&As[lr][lk]) = av;
    uint4 bv = *(const uint4*)(Bt + (size_t)(n0+lr)*ldb + kk + lk);
    *(uint4*)(&Bs[lr][lk]) = bv;
    __syncthreads();
    bf16x8 af = *(const bf16x8*)(&As[w*16 + (lane&15)][(lane>>4)*8]);
    #pragma unroll
    for (int ni=0; ni<4; ++ni){
      bf16x8 bfr = *(const bf16x8*)(&Bs[ni*16 + (lane&15)][(lane>>4)*8]);
      acc[ni] = MFMA(af, bfr, acc[ni], 0,0,0);
    }
    __syncthreads();
  }
  #pragma unroll
  for (int ni=0; ni<4; ++ni){
    #pragma unroll
    for (int r=0; r<4; ++r){
      int row = m0 + w*16 + (lane>>4)*4 + r;
      int col = n0 + ni*16 + (lane&15);
      if (row < M){
        float v = acc[ni][r];
        if (BIAS) v += bias[col];
        if (OUTF==0) Cf[(size_t)row*ldc + col] = v;
        else         Cb[(size_t)row*ldc + col] = f2b(v);
      }
    }
  }
}

// ---------------- 3-term split-precision 64x64 GEMM: (Ah+Al) x (Bh+Bl) ----------------
template<int OUTF>
__global__ __launch_bounds__(256) void k_gemm64s(
    const u16* __restrict__ Ah, const u16* __restrict__ Al, int lda,
    const u16* __restrict__ Bh, const u16* __restrict__ Bl, int ldb,
    float* __restrict__ Cf, u16* __restrict__ Cb, int ldc, int M, int K)
{
  __shared__ __align__(16) u16 Ash[64][40], Asl[64][40], Bsh[64][40], Bsl[64][40];
  int n0 = blockIdx.x*64, m0 = blockIdx.y*64;
  int tid = threadIdx.x, lane = tid & 63, w = tid>>6;
  int lr = tid>>2, lk = (tid&3)*8;
  f32x4 acc[4] = {};
  for (int kk=0; kk<K; kk+=32){
    uint4 avh = make_uint4(0,0,0,0), avl = make_uint4(0,0,0,0);
    int row = m0 + lr;
    if (row < M){
      avh = *(const uint4*)(Ah + (size_t)row*lda + kk + lk);
      avl = *(const uint4*)(Al + (size_t)row*lda + kk + lk);
    }
    *(uint4*)(&Ash[lr][lk]) = avh;
    *(uint4*)(&Asl[lr][lk]) = avl;
    *(uint4*)(&Bsh[lr][lk]) = *(const uint4*)(Bh + (size_t)(n0+lr)*ldb + kk + lk);
    *(uint4*)(&Bsl[lr][lk]) = *(const uint4*)(Bl + (size_t)(n0+lr)*ldb + kk + lk);
    __syncthreads();
    bf16x8 afh = *(const bf16x8*)(&Ash[w*16 + (lane&15)][(lane>>4)*8]);
    bf16x8 afl = *(const bf16x8*)(&Asl[w*16 + (lane&15)][(lane>>4)*8]);
    #pragma unroll
    for (int ni=0; ni<4; ++ni){
      bf16x8 bfh = *(const bf16x8*)(&Bsh[ni*16 + (lane&15)][(lane>>4)*8]);
      bf16x8 bfl = *(const bf16x8*)(&Bsl[ni*16 + (lane&15)][(lane>>4)*8]);
      acc[ni] = MFMA(afh, bfl, acc[ni], 0,0,0);
      acc[ni] = MFMA(afl, bfh, acc[ni], 0,0,0);
      acc[ni] = MFMA(afh, bfh, acc[ni], 0,0,0);
    }
    __syncthreads();
  }
  #pragma unroll
  for (int ni=0; ni<4; ++ni){
    #pragma unroll
    for (int r=0; r<4; ++r){
      int row = m0 + w*16 + (lane>>4)*4 + r;
      int col = n0 + ni*16 + (lane&15);
      if (row < M){
        float v = acc[ni][r];
        if (OUTF==0) Cf[(size_t)row*ldc + col] = v;
        else         Cb[(size_t)row*ldc + col] = f2b(v);
      }
    }
  }
}

// ---------------- persistent recurrence kernel ----------------
struct PP {
  const u16 *WzhTH, *WzhTL;   // [4096][1024]
  const u16 *WzcTH, *WzcTL;   // [4096][1024]
  const u16 *Wr0TH, *Wr0TL;   // [4096][1024] (t=0 h-weight = W_r^T)
  const u16 *WqT;             // [1024][1024]
  const u16 *xW;              // rows b*NT+t, 4096 cols (bf16, bias folded)
  const u16 *keys;            // [4096][1024]
  const u16 *aB;              // [4096][1024]
  const float *v_att;         // [1024]
  const u16 *h0H, *h0L;       // [32][1024]
  u16 *hH0,*hL0,*hH1,*hL1;    // ping-pong h
  u16 *ctxH, *ctxL;           // [32][1024] (zero-init)
  float *cbuf;                // [32][1024] (init c_tx)
  float *qf;                  // [32][1024]
  float *scf;                 // [32][128]
  u16 *hcH, *hcL;             // [4096][2048] hist [h | ctx]
  unsigned *bar;
};

// ---- two-level tree barrier with DISTRIBUTED spin lines ----
// layout (u32 indices, 256B-spaced lines): grp[g]=g*64, master=16*64, go[g]=(17+g)*64
// arrival: 16 blocks/group inc grp line; group-last incs master; global-last
// release-stores generation stamp to all 16 go lines; leaders spin on OWN go line
// (16 pollers/line instead of 256 on one line -> no home-slice serialization).
DEVI void gbar(unsigned* bars, unsigned gen){
  __syncthreads();
  if (threadIdx.x == 0){
    int g = blockIdx.x & 15;
    unsigned* grp = bars + g*64;
    unsigned* mst = bars + 16*64;
    unsigned* go  = bars + 17*64;
    unsigned v = __hip_atomic_fetch_add(grp, 1u, __ATOMIC_ACQ_REL, __HIP_MEMORY_SCOPE_AGENT);
    if (v + 1u == gen*16u){
      unsigned m = __hip_atomic_fetch_add(mst, 1u, __ATOMIC_ACQ_REL, __HIP_MEMORY_SCOPE_AGENT);
      if (m + 1u == gen*16u){
        __builtin_amdgcn_fence(__ATOMIC_RELEASE, "agent");
        #pragma unroll
        for (int i=0; i<16; ++i)
          __hip_atomic_store(go + i*64, gen, __ATOMIC_RELAXED, __HIP_MEMORY_SCOPE_AGENT);
      }
    }
    while (__hip_atomic_load(go + g*64, __ATOMIC_RELAXED, __HIP_MEMORY_SCOPE_AGENT) < gen)
      __builtin_amdgcn_s_sleep(2);
    __builtin_amdgcn_fence(__ATOMIC_ACQUIRE, "agent");
  }
  __syncthreads();
}

__global__ __launch_bounds__(512,1) void k_persist(PP p){
  __shared__ float smem[4096];   // 16 KB: zs[8][32][16] / alig[128]+psum[8][128]
  float (*zs)[32][16] = (float(*)[32][16])smem;
  int tid = threadIdx.x, lane = tid&63, wv = tid>>6, blk = blockIdx.x;
  int l15 = lane&15, ko = (lane>>4)*8;

  // ================= register preloads (fence-proof residency) =================
  // phase-A weight slice: 16 rows (4 gates x 4 u's), this wave's 256-k window
  int u0 = blk*4;
  int wrow = (l15>>2)*1024 + u0 + (l15&3);
  size_t woff = (size_t)wrow*1024 + (wv&3)*256 + ko;
  const u16 *whG = (wv<4 ? p.Wr0TH : p.WzcTH) + woff;
  const u16 *wlG = (wv<4 ? p.Wr0TL : p.WzcTL) + woff;
  bf16x8 wH[8], wL[8];
  #pragma unroll
  for (int ki=0; ki<8; ++ki){
    wH[ki] = *(const bf16x8*)(whG + ki*32);
    wL[ki] = *(const bf16x8*)(wlG + ki*32);
  }
  // phase-B Wq slice (blocks 0..63 only)
  bf16x8 wq[4];
  int nq0 = (blk&63)*16;
  if (blk < 64){
    const u16* qg = p.WqT + (size_t)(nq0+l15)*1024 + wv*128 + ko;
    #pragma unroll
    for (int ki=0; ki<4; ++ki) wq[ki] = *(const bf16x8*)(qg + ki*32);
  }
  // phase-C1 keys slice: block (b=blk>>3, sq=blk&7), wave rows sq*16+wv*2+{0,1}
  int cb = blk>>3, sq = blk&7;
  u16x8 kr[2][2];
  #pragma unroll
  for (int si=0; si<2; ++si){
    const u16* kp = p.keys + (size_t)(cb*128 + sq*16 + wv*2 + si)*1024 + lane*16;
    kr[si][0] = *(const u16x8*)kp;
    kr[si][1] = *(const u16x8*)(kp + 8);
  }
  // phase-C2 aB slice: block (b=cb, c0), thread (sq8=tid>>6, cp=2*(tid&63))
  int c0 = (blk&7)*128, cp = 2*(tid&63), sq8 = tid>>6;
  unsigned av[16];
  #pragma unroll
  for (int si=0; si<16; ++si)
    av[si] = *(const unsigned*)(p.aB + (size_t)(cb*128 + sq8*16 + si)*1024 + c0 + cp);

  unsigned gen = 0;
  const u16 *hpH = p.h0H, *hpL = p.h0L;
  for (int t=0; t<NT; ++t){
    u16* hoH = (t&1)? p.hH1 : p.hH0;
    u16* hoL = (t&1)? p.hL1 : p.hL0;
    // ---- phase A: z = xW + h@Wzh + ctx@Wzc -> gates -> h,c ----
    {
      const u16 *Ah = (wv<4)? hpH : p.ctxH;
      const u16 *Al = (wv<4)? hpL : p.ctxL;
      int kb = (wv&3)*256;
      f32x4 acc0 = {}, acc1 = {};
      #pragma unroll
      for (int ki=0; ki<8; ++ki){
        int kl = kb + ki*32 + ko;
        bf16x8 a0h = *(const bf16x8*)(Ah + (size_t)l15*1024 + kl);
        bf16x8 a1h = *(const bf16x8*)(Ah + (size_t)(l15+16)*1024 + kl);
        bf16x8 a0l = *(const bf16x8*)(Al + (size_t)l15*1024 + kl);
        bf16x8 a1l = *(const bf16x8*)(Al + (size_t)(l15+16)*1024 + kl);
        acc0 = MFMA(a0h, wL[ki], acc0, 0,0,0);
        acc0 = MFMA(a0l, wH[ki], acc0, 0,0,0);
        acc0 = MFMA(a0h, wH[ki], acc0, 0,0,0);
        acc1 = MFMA(a1h, wL[ki], acc1, 0,0,0);
        acc1 = MFMA(a1l, wH[ki], acc1, 0,0,0);
        acc1 = MFMA(a1h, wH[ki], acc1, 0,0,0);
      }
      // after t=0 consumed Wr0, swap in the steady-state Wzh (hidden by B/C phases)
      if (t == 0 && wv < 4){
        const u16* nh = p.WzhTH + woff;
        const u16* nl = p.WzhTL + woff;
        #pragma unroll
        for (int ki=0; ki<8; ++ki){
          wH[ki] = *(const bf16x8*)(nh + ki*32);
          wL[ki] = *(const bf16x8*)(nl + ki*32);
        }
      }
      #pragma unroll
      for (int r=0; r<4; ++r){
        zs[wv][(lane>>4)*4 + r][l15]      = acc0[r];
        zs[wv][16 + (lane>>4)*4 + r][l15] = acc1[r];
      }
      __syncthreads();
      if (tid < 128){
        int b = tid>>2, du = tid&3;
        const u16* xw = p.xW + (size_t)(b*NT + t)*4096;
        float zg[4];
        #pragma unroll
        for (int g=0; g<4; ++g){
          float v = 0.f;
          #pragma unroll
          for (int w=0; w<8; ++w) v += zs[w][b][g*4+du];
          zg[g] = v + b2f(xw[g*1024 + u0 + du]);
        }
        float i_ = sigm(zg[0]), f_ = sigm(zg[1]), g_ = tanh_(zg[2]), o_ = sigm(zg[3]);
        int ci = b*NU + u0 + du;
        float cn = f_*p.cbuf[ci] + i_*g_;
        p.cbuf[ci] = cn;
        float h = o_*tanh_(cn);
        u16 hi = f2b(h), lo = f2b(h - b2f(hi));
        hoH[ci] = hi; hoL[ci] = lo;
        size_t ho = (size_t)(b*NT + t)*2048 + u0 + du;
        p.hcH[ho] = hi; p.hcL[ho] = lo;
      }
    }
    ++gen; gbar(p.bar, gen);
    // ---- phase B: q = h@W_q (blocks 0..63) ----
    if (blk < 64){
      f32x4 acc0 = {}, acc1 = {};
      #pragma unroll
      for (int ki=0; ki<4; ++ki){
        int kk = wv*128 + ki*32 + ko;
        bf16x8 a0h = *(const bf16x8*)(hoH + (size_t)l15*1024 + kk);
        bf16x8 a1h = *(const bf16x8*)(hoH + (size_t)(l15+16)*1024 + kk);
        bf16x8 a0l = *(const bf16x8*)(hoL + (size_t)l15*1024 + kk);
        bf16x8 a1l = *(const bf16x8*)(hoL + (size_t)(l15+16)*1024 + kk);
        acc0 = MFMA(a0l, wq[ki], acc0, 0,0,0);
        acc0 = MFMA(a0h, wq[ki], acc0, 0,0,0);
        acc1 = MFMA(a1l, wq[ki], acc1, 0,0,0);
        acc1 = MFMA(a1h, wq[ki], acc1, 0,0,0);
      }
      #pragma unroll
      for (int r=0; r<4; ++r){
        zs[wv][(lane>>4)*4 + r][l15]      = acc0[r];
        zs[wv][16 + (lane>>4)*4 + r][l15] = acc1[r];
      }
      __syncthreads();
      {
        int b = tid>>4, c = tid&15;
        float v = 0.f;
        #pragma unroll
        for (int w=0; w<8; ++w) v += zs[w][b][c];
        p.qf[b*NU + nq0 + c] = v;
      }
    }
    ++gen; gbar(p.bar, gen);
    // ---- phase C1: scores (keys in registers) ----
    {
      float qr[16], vr[16];
      #pragma unroll
      for (int j=0; j<4; ++j){
        *(float4*)&qr[j*4] = *(const float4*)(p.qf + cb*NU + lane*16 + j*4);
        *(float4*)&vr[j*4] = *(const float4*)(p.v_att + lane*16 + j*4);
      }
      #pragma unroll
      for (int si=0; si<2; ++si){
        float pv = 0.f;
        #pragma unroll
        for (int j=0; j<8; ++j) pv += vr[j]   * tanh_(b2f(kr[si][0][j]) + qr[j]);
        #pragma unroll
        for (int j=0; j<8; ++j) pv += vr[8+j] * tanh_(b2f(kr[si][1][j]) + qr[8+j]);
        #pragma unroll
        for (int off=32; off; off>>=1) pv += __shfl_xor(pv, off);
        if (lane==0) p.scf[cb*128 + sq*16 + wv*2 + si] = pv;
      }
    }
    ++gen; gbar(p.bar, gen);
    // ---- phase C2: softmax + ctx (aB in registers) ----
    {
      float* alig = smem;
      float* psum = smem + 128;
      if (tid < 64){
        float s0 = p.scf[cb*128 + tid], s1 = p.scf[cb*128 + 64 + tid];
        float m = fmaxf(s0, s1);
        #pragma unroll
        for (int off=32; off; off>>=1) m = fmaxf(m, __shfl_xor(m, off));
        float e0 = __expf(s0-m), e1 = __expf(s1-m);
        float sum = e0+e1;
        #pragma unroll
        for (int off=32; off; off>>=1) sum += __shfl_xor(sum, off);
        float inv = 1.f/sum;
        alig[tid] = e0*inv; alig[tid+64] = e1*inv;
      }
      __syncthreads();
      {
        float ax = 0.f, ay = 0.f;
        #pragma unroll
        for (int si=0; si<16; ++si){
          unsigned kv = av[si];
          float al = alig[sq8*16 + si];
          ax += al*b2f((u16)(kv & 0xffffu));
          ay += al*b2f((u16)(kv >> 16));
        }
        psum[sq8*128 + cp]   = ax;
        psum[sq8*128 + cp+1] = ay;
      }
      __syncthreads();
      if (tid < 128){
        float v = 0.f;
        #pragma unroll
        for (int s8=0; s8<8; ++s8) v += psum[s8*128 + tid];
        int col = c0 + tid, ci = cb*NU + col;
        u16 hi = f2b(v), lo = f2b(v - b2f(hi));
        p.ctxH[ci] = hi; p.ctxL[ci] = lo;
        size_t ho = (size_t)(cb*NT + t)*2048 + 1024 + col;
        p.hcH[ho] = hi; p.hcL[ho] = lo;
      }
    }
    ++gen; gbar(p.bar, gen);
    hpH = hoH; hpL = hoL;
  }
}

// ---------------- logits: 128x128-tile, BK=64, double-buffered reg-staged ----------------
#define LDSK 72
__global__ __launch_bounds__(256) void k_logits(
    const u16* __restrict__ A,   // [4096][1024]
    const u16* __restrict__ Bt,  // [32000][1024]
    const float* __restrict__ bias,
    float* __restrict__ C)
{
  __shared__ __align__(16) u16 As[128*LDSK];
  __shared__ __align__(16) u16 Bs[128*LDSK];
  int tid = threadIdx.x, lane = tid&63, wv = tid>>6;
  int m0 = blockIdx.y*128, n0 = blockIdx.x*128;
  int wr = (wv>>1)*64, wc = (wv&1)*64;
  int l15 = lane&15, ko = (lane>>4)*8;
  int srow = tid>>3, sc8 = (tid&7)*8;
  f32x4 acc[4][4] = {};
  uint4 a0[4], b0[4], a1[4], b1[4];

  #define LOADG(ar, br, kk) { \
    _Pragma("unroll") \
    for (int i=0;i<4;++i){ \
      ar[i] = *(const uint4*)(A  + (size_t)(m0+srow+i*32)*1024 + (kk) + sc8); \
      br[i] = *(const uint4*)(Bt + (size_t)(n0+srow+i*32)*1024 + (kk) + sc8); \
    } }
  #define STORES(ar, br) { \
    _Pragma("unroll") \
    for (int i=0;i<4;++i){ \
      *(uint4*)(&As[(srow+i*32)*LDSK + sc8]) = ar[i]; \
      *(uint4*)(&Bs[(srow+i*32)*LDSK + sc8]) = br[i]; \
    } }
  #define COMPUTE() { \
    _Pragma("unroll") \
    for (int ks=0; ks<2; ++ks){ \
      bf16x8 af[4], bf[4]; \
      _Pragma("unroll") \
      for (int i=0;i<4;++i){ \
        af[i] = *(const bf16x8*)(&As[(wr+i*16+l15)*LDSK + ks*32 + ko]); \
        bf[i] = *(const bf16x8*)(&Bs[(wc+i*16+l15)*LDSK + ks*32 + ko]); \
      } \
      _Pragma("unroll") \
      for (int mi=0;mi<4;++mi) \
        _Pragma("unroll") \
        for (int ni=0;ni<4;++ni) \
          acc[mi][ni] = MFMA(af[mi], bf[ni], acc[mi][ni], 0,0,0); \
    } }

  LOADG(a0, b0, 0);
  for (int kk=0; kk<1024; kk+=128){
    __syncthreads();
    STORES(a0, b0);
    if (kk+64 < 1024) LOADG(a1, b1, kk+64);
    __syncthreads();
    COMPUTE();
    __syncthreads();
    STORES(a1, b1);
    if (kk+128 < 1024) LOADG(a0, b0, kk+128);
    __syncthreads();
    COMPUTE();
  }
  #pragma unroll
  for (int mi=0; mi<4; ++mi){
    int row = m0 + wr + mi*16 + (lane>>4)*4;
    #pragma unroll
    for (int ni=0; ni<4; ++ni){
      int col = n0 + wc + ni*16 + l15;
      float bval = bias[col];
      #pragma unroll
      for (int r=0; r<4; ++r){
        if (row + r < NB*NT)
          C[(size_t)(row+r)*NV + col] = acc[mi][ni][r] + bval;
      }
    }
  }
  #undef LOADG
  #undef STORES
  #undef COMPUTE
}

// ---------------- host ----------------
extern "C" void kernel_launch(void* const* d_in, const int* in_sizes, int n_in,
                              void* d_out, int out_size, void* d_ws, size_t ws_size,
                              hipStream_t stream)
{
  (void)in_sizes; (void)n_in; (void)out_size; (void)ws_size;
  const int*   toks  = (const int*)  d_in[0];
  const float* a_in  = (const float*)d_in[1];
  const float* a_tx  = (const float*)d_in[2];
  const float* c_tx  = (const float*)d_in[3];
  const float* emb   = (const float*)d_in[4];
  const float* W_k   = (const float*)d_in[5];
  const float* W_r   = (const float*)d_in[6];
  const float* bvec  = (const float*)d_in[7];
  const float* W_m   = (const float*)d_in[8];
  const float* W_q   = (const float*)d_in[9];
  const float* v_att = (const float*)d_in[10];
  const float* W_a   = (const float*)d_in[11];
  const float* W_o   = (const float*)d_in[12];
  const float* b_o   = (const float*)d_in[13];
  float* out = (float*)d_out;

  char* p = (char*)d_ws;
  auto alloc = [&](size_t bytes)->char*{ char* r = p; p += (bytes + 255) & ~(size_t)255; return r; };

  u16* WzhTH = (u16*)alloc((size_t)4096*1024*2);
  u16* WzhTL = (u16*)alloc((size_t)4096*1024*2);
  u16* WzcTH = (u16*)alloc((size_t)4096*1024*2);
  u16* WzcTL = (u16*)alloc((size_t)4096*1024*2);
  u16* Wr0TH = (u16*)alloc((size_t)4096*1024*2);   // reused as outsH after persist
  u16* Wr0TL = (u16*)alloc((size_t)4096*1024*2);
  u16* WqT   = (u16*)alloc((size_t)1024*1024*2);
  u16* WaTH  = (u16*)alloc((size_t)1024*2048*2);
  u16* WaTL  = (u16*)alloc((size_t)1024*2048*2);
  u16* WmT   = (u16*)alloc((size_t)1024*1024*2);
  u16* WoT   = (u16*)alloc((size_t)NV*1024*2);
  u16* WkxT  = (u16*)alloc((size_t)4096*256*2);
  u16* xB    = (u16*)alloc((size_t)4096*256*2);
  u16* xWb   = (u16*)alloc((size_t)4096*4096*2);
  u16* aB    = (u16*)alloc((size_t)4096*1024*2);
  u16* keysB = (u16*)alloc((size_t)4096*1024*2);
  // union region: prep { WkaT h/l, WaRow h/l, tmpF } -> persist { hcH, hcL }
  char* uni  = alloc((size_t)44*1024*1024);
  u16* WkaTH  = (u16*)uni;
  u16* WkaTL  = WkaTH + (size_t)4096*1024;
  u16* WaRowH = WkaTL + (size_t)4096*1024;
  u16* WaRowL = WaRowH + (size_t)2048*1024;
  float* tmpF = (float*)(WaRowL + (size_t)2048*1024);
  u16* hcH = (u16*)uni;
  u16* hcL = hcH + (size_t)4096*2048;

  u16* h0H  = (u16*)alloc((size_t)NB*NU*2);
  u16* h0L  = (u16*)alloc((size_t)NB*NU*2);
  u16* hH0  = (u16*)alloc((size_t)NB*NU*2);
  u16* hL0  = (u16*)alloc((size_t)NB*NU*2);
  u16* hH1  = (u16*)alloc((size_t)NB*NU*2);
  u16* hL1  = (u16*)alloc((size_t)NB*NU*2);
  u16* ctxH = (u16*)alloc((size_t)NB*NU*2);
  u16* ctxL = (u16*)alloc((size_t)NB*NU*2);
  float* cbuf = (float*)alloc((size_t)NB*NU*4);
  float* qf   = (float*)alloc((size_t)NB*NU*4);
  float* scf  = (float*)alloc((size_t)NB*128*4);
  unsigned* bar = (unsigned*)alloc(16384);
  u16* outsH = Wr0TH;   // overlap (Wr0T dead after persistent kernel)

  // ---- init ----
  hipMemsetAsync(bar, 0, 16384, stream);
  hipMemsetAsync(ctxH, 0, (size_t)NB*NU*2, stream);
  hipMemsetAsync(ctxL, 0, (size_t)NB*NU*2, stream);
  hipMemcpyAsync(cbuf, c_tx, (size_t)NB*NU*4, hipMemcpyDeviceToDevice, stream);
  k_split<<<128,256,0,stream>>>(a_tx, h0H, h0L, NB*NU);
  k_split<<<2048,256,0,stream>>>(W_a, WaRowH, WaRowL, 2048*1024);
  k_gather<<<(NB*NT*NE)/256,256,0,stream>>>(toks, emb, xB);
  k_conv<<<2048,256,0,stream>>>(a_in, aB, NB*128*NU);

  // ---- weight transposes ----
  k_transpose<<<dim3(128,32),256,0,stream>>>(W_k + (size_t)256*4096, 4096, WkaTH, WkaTL, 1024, 0);
  k_transpose<<<dim3(128,32),256,0,stream>>>(W_r, 4096, Wr0TH, Wr0TL, 1024, 0);
  k_transpose<<<dim3(32,32),256,0,stream>>>(W_q, 1024, WqT, nullptr, 1024, 0);
  k_transpose<<<dim3(32,64),256,0,stream>>>(W_a, 1024, WaTH, WaTL, 2048, 0);
  k_transpose<<<dim3(32,32),256,0,stream>>>(W_m, 1024, WmT, nullptr, 1024, 0);
  k_transpose<<<dim3(1000,32),256,0,stream>>>(W_o, NV, WoT, nullptr, 1024, 0);
  k_transpose<<<dim3(128,8),256,0,stream>>>(W_k, 4096, WkxT, nullptr, 256, 0);

  // ---- precompute GEMMs ----
  // keys = a @ W_m
  k_gemm64<1,0><<<dim3(16,64),256,0,stream>>>(aB, 1024, WmT, 1024, nullptr, keysB, 1024, nullptr, 4096, 1024);
  // xW = x @ W_k[0:256] + b
  k_gemm64<1,1><<<dim3(64,64),256,0,stream>>>(xB, 256, WkxT, 256, nullptr, xWb, 4096, bvec, NB*NT, 256);
  // Wzh = W_r + W_a[0:1024] @ Wk_attn  (3-term split, f32, then transpose+split)
  k_gemm64s<0><<<dim3(64,16),256,0,stream>>>(WaRowH, WaRowL, 1024, WkaTH, WkaTL, 1024,
                                             tmpF, nullptr, 4096, 1024, 1024);
  k_fuseT<<<dim3(128,32),256,0,stream>>>(tmpF, W_r, WzhTH, WzhTL);
  // Wzc = W_a[1024:2048] @ Wk_attn
  k_gemm64s<0><<<dim3(64,16),256,0,stream>>>(WaRowH + (size_t)1024*1024, WaRowL + (size_t)1024*1024, 1024,
                                             WkaTH, WkaTL, 1024, tmpF, nullptr, 4096, 1024, 1024);
  k_fuseT<<<dim3(128,32),256,0,stream>>>(tmpF, nullptr, WzcTH, WzcTL);

  // ---- persistent recurrence ----
  PP pp;
  pp.WzhTH=WzhTH; pp.WzhTL=WzhTL; pp.WzcTH=WzcTH; pp.WzcTL=WzcTL;
  pp.Wr0TH=Wr0TH; pp.Wr0TL=Wr0TL; pp.WqT=WqT; pp.xW=xWb;
  pp.keys=keysB; pp.aB=aB; pp.v_att=v_att;
  pp.h0H=h0H; pp.h0L=h0L;
  pp.hH0=hH0; pp.hL0=hL0; pp.hH1=hH1; pp.hL1=hL1;
  pp.ctxH=ctxH; pp.ctxL=ctxL; pp.cbuf=cbuf; pp.qf=qf; pp.scf=scf;
  pp.hcH=hcH; pp.hcL=hcL; pp.bar=bar;
  k_persist<<<NBLK,512,0,stream>>>(pp);

  // ---- outs = [h|ctx] @ W_a  (3-term split, bf16 out) ----
  k_gemm64s<1><<<dim3(16,64),256,0,stream>>>(hcH, hcL, 2048, WaTH, WaTL, 2048,
                                             nullptr, outsH, 1024, NB*NT, 2048);

  // ---- logits = outs @ W_o + b_o ----
  k_logits<<<dim3(NV/128, 32),256,0,stream>>>(outsH, WoT, b_o, out);
}